// Round 11
// baseline (72.563 us; speedup 1.0000x reference)
//
#include <hip/hip_runtime.h>

#define BB 4
#define CC 64
#define C2 32            // channel pairs
#define HH 64
#define WW 64
#define PATCH 9
#define HALF 4
#define P2 81
#define HW 4096
#define IMG (CC * HW)

typedef _Float16 v2h __attribute__((ext_vector_type(2)));
typedef __fp16 v2fp __attribute__((ext_vector_type(2)));

static __device__ __forceinline__ unsigned pkrtz(float a, float b) {
    v2fp h = __builtin_amdgcn_cvt_pkrtz(a, b);   // single v_cvt_pkrtz_f16_f32
    return __builtin_bit_cast(unsigned, h);
}

// One block per (b, y, dy): 2304 blocks x 192 threads (3 waves).
// Wave w owns taps dx in {3w, 3w+1, 3w+2} over ALL channels -> no cross-wave
// accumulator reduction. 27 waves/CU for latency hiding (vs 9 in the
// single-wave design). XCD swizzle: xcd = bid & 7 owns y-octave.
__global__ __launch_bounds__(192) void corr_kernel(const float* __restrict__ f1,
                                                   const float* __restrict__ f2,
                                                   float* __restrict__ out) {
    __shared__ unsigned sB[C2 * 72];   // [c2][72 cols]; cols 0..3,68..71 zero (9.2 KB)
    __shared__ float sS2[64];          // f2 column inverse norms (real cols)

    const int tid = threadIdx.x;
    const int x   = tid & 63;
    const int w   = tid >> 6;          // wave 0..2
    const int bid = blockIdx.x;
    const int xcd = bid & 7;
    const int s   = bid >> 3;          // 0..287
    const int b   = s / 72;
    const int r   = s - b * 72;
    const int yo  = r / 9;
    const int dy  = r - yo * 9;
    const int y   = xcd * 8 + yo;
    const int y2  = y + dy - HALF;

    float* ob = out + b * (P2 * HW) + y * WW + x;

    if ((unsigned)y2 >= HH) {          // whole dy-row OOB -> zeros (all taps covered)
#pragma unroll
        for (int j = 0; j < 3; ++j)
            ob[(dy * PATCH + 3 * w + j) * HW] = 0.f;
        return;
    }

    // ---- cooperative stage of f2 row y2 into sB[c2][72] (packed f16x2) ----
    const float* f2r = f2 + b * IMG + y2 * WW;
    for (int item = tid; item < 512; item += 192) {
        int c2 = item >> 4, k = item & 15;
        const float* p = f2r + 4 * k;
        float4 va = *(const float4*)(p + (2 * c2) * HW);
        float4 vb = *(const float4*)(p + (2 * c2 + 1) * HW);
        uint4 u = {pkrtz(va.x, vb.x), pkrtz(va.y, vb.y),
                   pkrtz(va.z, vb.z), pkrtz(va.w, vb.w)};
        *(uint4*)&sB[c2 * 72 + 4 + 4 * k] = u;
    }
    for (int j = tid; j < 256; j += 192) {   // zero pads: cols 0..3, 68..71
        int c2 = j >> 3, e = j & 7;
        sB[c2 * 72 + (e < 4 ? e : 64 + e)] = 0u;
    }

    // ---- f1 row -> registers (each wave redundantly; L1-shared) ----
    const float* f1r = f1 + b * IMG + y * WW + x;
    unsigned a[C2];
    float ssq1 = 0.f;
#pragma unroll
    for (int c2 = 0; c2 < C2; ++c2) {
        float u0 = f1r[(2 * c2) * HW];
        float u1 = f1r[(2 * c2 + 1) * HW];
        a[c2] = pkrtz(u0, u1);
        v2h a2 = __builtin_bit_cast(v2h, a[c2]);
        ssq1 = __builtin_amdgcn_fdot2(a2, a2, ssq1, false);
    }
    __syncthreads();

    // ---- wave 0: f2 column inverse norms from LDS center taps ----
    if (w == 0) {
        float ss = 0.f;
#pragma unroll
        for (int c2 = 0; c2 < C2; ++c2) {
            v2h v = __builtin_bit_cast(v2h, sB[c2 * 72 + 4 + x]);  // real col x
            ss = __builtin_amdgcn_fdot2(v, v, ss, false);
        }
        sS2[x] = rsqrtf(ss + 1e-6f);
    }

    // ---- main loop: 32 c2 x 3 taps per wave ----
    float acc0 = 0.f, acc1 = 0.f, acc2 = 0.f;
    const int boff = x + 3 * w;        // padded col of this wave's tap 0
#pragma unroll
    for (int c2 = 0; c2 < C2; ++c2) {
        v2h a2 = __builtin_bit_cast(v2h, a[c2]);
        const unsigned* br = &sB[c2 * 72 + boff];
        acc0 = __builtin_amdgcn_fdot2(a2, __builtin_bit_cast(v2h, br[0]), acc0, false);
        acc1 = __builtin_amdgcn_fdot2(a2, __builtin_bit_cast(v2h, br[1]), acc1, false);
        acc2 = __builtin_amdgcn_fdot2(a2, __builtin_bit_cast(v2h, br[2]), acc2, false);
    }
    __syncthreads();                   // sS2 ready

    const float s1 = rsqrtf(ssq1 + 1e-6f);
    float accs[3] = {acc0, acc1, acc2};
#pragma unroll
    for (int j = 0; j < 3; ++j) {
        int dx = 3 * w + j;
        int col = x + dx - HALF;
        col = min(max(col, 0), WW - 1);          // OOB taps have acc==0
        ob[(dy * PATCH + dx) * HW] = fmaxf(accs[j] * s1 * sS2[col], 0.f);
    }
}

extern "C" void kernel_launch(void* const* d_in, const int* in_sizes, int n_in,
                              void* d_out, int out_size, void* d_ws, size_t ws_size,
                              hipStream_t stream) {
    const float* f1 = (const float*)d_in[0];
    const float* f2 = (const float*)d_in[1];
    float* out = (float*)d_out;
    (void)d_ws; (void)ws_size;

    corr_kernel<<<BB * HH * PATCH, 192, 0, stream>>>(f1, f2, out);
}

// Round 12
// 69.925 us; speedup vs baseline: 1.0377x; 1.0377x over previous
//
#include <hip/hip_runtime.h>

#define BB 4
#define CC 64
#define C2 32            // channel pairs
#define HH 64
#define WW 64
#define PATCH 9
#define HALF 4
#define P2 81
#define HW 4096
#define IMG (CC * HW)

typedef _Float16 v2h __attribute__((ext_vector_type(2)));
typedef __fp16 v2fp __attribute__((ext_vector_type(2)));

static __device__ __forceinline__ unsigned pkrtz(float a, float b) {
    v2fp h = __builtin_amdgcn_cvt_pkrtz(a, b);   // single v_cvt_pkrtz_f16_f32
    return __builtin_bit_cast(unsigned, h);
}
static __device__ __forceinline__ float fdot2u(unsigned a, unsigned b, float acc) {
    return __builtin_amdgcn_fdot2(__builtin_bit_cast(v2h, a),
                                  __builtin_bit_cast(v2h, b), acc, false);
}

// Single-wave block per (b, y-pair, d): 1280 blocks x 64 threads.
// Outputs (y0, dy=d) [d<=8] and (y0+1, dy=d-1) [d>=1] share f2 row
// y2 = y0+d-4 AND the same padded tap columns -> one staging + one set of
// tap reads feeds 18 accumulators (total LDS reads halved vs per-(y,dy)).
// XCD swizzle: xcd = bid & 7 owns y-octave [8*xcd, 8*xcd+8).
__global__ __launch_bounds__(64) void corr_kernel(const float* __restrict__ f1,
                                                  const float* __restrict__ f2,
                                                  float* __restrict__ out) {
    __shared__ unsigned sB[C2 * 72];   // [c2][72 cols]; cols 0..3,68..71 zero (9.2 KB)
    __shared__ float sS2[64];          // f2 column inverse norms (real cols)

    const int x   = threadIdx.x;       // 0..63
    const int bid = blockIdx.x;
    const int xcd = bid & 7;
    const int s   = bid >> 3;          // 0..159
    const int b   = s / 40;
    const int r   = s - b * 40;        // 0..39
    const int yp  = r / 10;            // 0..3
    const int d   = r - yp * 10;       // 0..9
    const int y0  = xcd * 8 + yp * 2;  // even row
    const int y2  = y0 + d - HALF;     // shared f2 row

    const bool has0 = (d <= 8);        // output (y0,   dy=d)
    const bool has1 = (d >= 1);        // output (y0+1, dy=d-1)

    float* ob0 = out + b * (P2 * HW) + y0 * WW + x;
    float* ob1 = ob0 + WW;

    if ((unsigned)y2 >= HH) {          // shared row OOB -> both outputs zero
        if (has0)
#pragma unroll
            for (int dx = 0; dx < PATCH; ++dx) ob0[(d * PATCH + dx) * HW] = 0.f;
        if (has1)
#pragma unroll
            for (int dx = 0; dx < PATCH; ++dx) ob1[((d - 1) * PATCH + dx) * HW] = 0.f;
        return;
    }

    // ---- stage f2 row y2 into sB [c2][72] packed f16x2, zero pads ----
    const float* f2r = f2 + b * IMG + y2 * WW;
#pragma unroll
    for (int it = 0; it < 8; ++it) {
        int item = x + it * 64;        // 512 items: (c2, k)
        int c2 = item >> 4, k = item & 15;
        const float* p = f2r + 4 * k;
        float4 va = *(const float4*)(p + (2 * c2) * HW);
        float4 vb = *(const float4*)(p + (2 * c2 + 1) * HW);
        uint4 u = {pkrtz(va.x, vb.x), pkrtz(va.y, vb.y),
                   pkrtz(va.z, vb.z), pkrtz(va.w, vb.w)};
        *(uint4*)&sB[c2 * 72 + 4 + 4 * k] = u;
    }
#pragma unroll
    for (int it = 0; it < 4; ++it) {   // 256 pad dwords: cols 0..3 and 68..71
        int j = x + it * 64;
        int c2 = j >> 3, e = j & 7;
        sB[c2 * 72 + (e < 4 ? e : 64 + e)] = 0u;
    }

    // ---- f1 rows y0, y0+1 -> packed registers + ssq ----
    const float* f1r0 = f1 + b * IMG + y0 * WW + x;
    unsigned a0[C2], a1[C2];
    float ssq1a = 0.f, ssq1b = 0.f;
#pragma unroll
    for (int c2 = 0; c2 < C2; ++c2) {
        float u0 = f1r0[(2 * c2) * HW];
        float u1 = f1r0[(2 * c2 + 1) * HW];
        a0[c2] = pkrtz(u0, u1);
        ssq1a = fdot2u(a0[c2], a0[c2], ssq1a);
        float w0 = f1r0[(2 * c2) * HW + WW];
        float w1 = f1r0[(2 * c2 + 1) * HW + WW];
        a1[c2] = pkrtz(w0, w1);
        ssq1b = fdot2u(a1[c2], a1[c2], ssq1b);
    }
    __syncthreads();                   // single wave: just a waitcnt

    // ---- main loop: 32 c2 x 9 taps x 2 rows; shared tap reads ----
    float acc0[PATCH], acc1[PATCH];
#pragma unroll
    for (int i = 0; i < PATCH; ++i) { acc0[i] = 0.f; acc1[i] = 0.f; }
    float ssq2 = 0.f;
#pragma unroll
    for (int c2 = 0; c2 < C2; ++c2) {
        const unsigned* br = &sB[c2 * 72 + x];   // tap dx at padded col x+dx
        unsigned p0 = a0[c2], p1 = a1[c2];
#pragma unroll
        for (int dx = 0; dx < PATCH; ++dx) {
            unsigned bv = br[dx];
            acc0[dx] = fdot2u(p0, bv, acc0[dx]);
            acc1[dx] = fdot2u(p1, bv, acc1[dx]);
        }
        ssq2 = fdot2u(br[4], br[4], ssq2);       // padded col x+4 == real col x
    }
    sS2[x] = rsqrtf(ssq2 + 1e-6f);
    __syncthreads();                   // intra-wave LDS visibility

    const float s1a = rsqrtf(ssq1a + 1e-6f);
    const float s1b = rsqrtf(ssq1b + 1e-6f);
#pragma unroll
    for (int dx = 0; dx < PATCH; ++dx) {
        int col = x + dx - HALF;
        col = min(max(col, 0), WW - 1);          // OOB taps have acc==0
        float s2 = sS2[col];
        if (has0) ob0[(d * PATCH + dx) * HW] = fmaxf(acc0[dx] * s1a * s2, 0.f);
        if (has1) ob1[((d - 1) * PATCH + dx) * HW] = fmaxf(acc1[dx] * s1b * s2, 0.f);
    }
}

extern "C" void kernel_launch(void* const* d_in, const int* in_sizes, int n_in,
                              void* d_out, int out_size, void* d_ws, size_t ws_size,
                              hipStream_t stream) {
    const float* f1 = (const float*)d_in[0];
    const float* f2 = (const float*)d_in[1];
    float* out = (float*)d_out;
    (void)d_ws; (void)ws_size;

    corr_kernel<<<BB * (HH / 2) * (PATCH + 1), 64, 0, stream>>>(f1, f2, out);
}

// Round 13
// 66.081 us; speedup vs baseline: 1.0981x; 1.0582x over previous
//
#include <hip/hip_runtime.h>

#define BB 4
#define CC 64
#define C2 32            // channel pairs
#define HH 64
#define WW 64
#define PATCH 9
#define HALF 4
#define P2 81
#define HW 4096
#define IMG (CC * HW)

typedef _Float16 v2h __attribute__((ext_vector_type(2)));
typedef __fp16 v2fp __attribute__((ext_vector_type(2)));

static __device__ __forceinline__ unsigned pkrtz(float a, float b) {
    v2fp h = __builtin_amdgcn_cvt_pkrtz(a, b);   // single v_cvt_pkrtz_f16_f32
    return __builtin_bit_cast(unsigned, h);
}

// BEST VARIANT (R10, 66.0-66.1 us): one SINGLE-WAVE block per (b, y, dy),
// 2304 blocks x 64 threads. XCD-aware decode: xcd = blockIdx % 8 owns
// y-octave [8*xcd, 8*xcd+8) for all (b, dy) -> per-XCD working set ~1.5 MB
// fits 4 MB L2, so the 9x staging redundancy is served by L2 not HBM (R8: -1.9us).
// f1 row in registers (f16x2), f2 row in 9.2 KB LDS, fdot2 inner loop.
// Rejected by measurement: 3-wave tap split (+6.5us), y-pair merge (+3.8us),
// VALU micro-opts (neutral) -> kernel is near its latency floor.
__global__ __launch_bounds__(64) void corr_kernel(const float* __restrict__ f1,
                                                  const float* __restrict__ f2,
                                                  float* __restrict__ out) {
    __shared__ unsigned sB[C2 * 72];   // [c2][72 cols]; cols 0..3,68..71 zero (9.2 KB)
    __shared__ float sS2[64];          // f2 column inverse norms (real cols)

    const int x   = threadIdx.x;       // 0..63
    const int bid = blockIdx.x;
    const int xcd = bid & 7;
    const int s   = bid >> 3;          // 0..287
    const int b   = s / 72;
    const int r   = s - b * 72;        // 0..71
    const int yo  = r / 9;
    const int dy  = r - yo * 9;
    const int y   = xcd * 8 + yo;
    const int y2  = y + dy - HALF;

    float* ob = out + b * (P2 * HW) + y * WW + x;

    if ((unsigned)y2 >= HH) {          // whole dy-row out of bounds -> zeros
#pragma unroll
        for (int dx = 0; dx < PATCH; ++dx)
            ob[(dy * PATCH + dx) * HW] = 0.f;
        return;
    }

    // ---- issue f2 row loads first (longest dependency chain) ----
    const float* f2r = f2 + b * IMG + y2 * WW;
    float4 va[8], vb[8];
#pragma unroll
    for (int it = 0; it < 8; ++it) {
        int item = x + it * 64;        // 512 items: (c2, k)
        int c2 = item >> 4, k = item & 15;
        const float* p = f2r + 4 * k;
        va[it] = *(const float4*)(p + (2 * c2) * HW);
        vb[it] = *(const float4*)(p + (2 * c2 + 1) * HW);
    }

    // ---- f1 row -> registers (issued while f2 is in flight) ----
    const float* f1r = f1 + b * IMG + y * WW + x;
    float u[CC];
#pragma unroll
    for (int c = 0; c < CC; ++c) u[c] = f1r[c * HW];

    // ---- pack + stage f2 into LDS [c2][72], zero pads ----
#pragma unroll
    for (int it = 0; it < 8; ++it) {
        int item = x + it * 64;
        int c2 = item >> 4, k = item & 15;
        uint4 w = {pkrtz(va[it].x, vb[it].x), pkrtz(va[it].y, vb[it].y),
                   pkrtz(va[it].z, vb[it].z), pkrtz(va[it].w, vb[it].w)};
        *(uint4*)&sB[c2 * 72 + 4 + 4 * k] = w;
    }
#pragma unroll
    for (int it = 0; it < 4; ++it) {   // 256 pad dwords: cols 0..3 and 68..71
        int j = x + it * 64;
        int c2 = j >> 3, e = j & 7;
        sB[c2 * 72 + (e < 4 ? e : 64 + e)] = 0u;
    }

    // ---- pack f1 + ssq1 via fdot2 on packed values ----
    unsigned a[C2];
    float ssq1 = 0.f;
#pragma unroll
    for (int c2 = 0; c2 < C2; ++c2) {
        a[c2] = pkrtz(u[2 * c2], u[2 * c2 + 1]);
        v2h a2 = __builtin_bit_cast(v2h, a[c2]);
        ssq1 = __builtin_amdgcn_fdot2(a2, a2, ssq1, false);
    }
    __syncthreads();                   // single wave: just a waitcnt

    // ---- main loop: 32 c2 x 9 taps, v_dot2_f32_f16; f2 col ssq on the fly ----
    float acc[PATCH];
#pragma unroll
    for (int i = 0; i < PATCH; ++i) acc[i] = 0.f;
    float ssq2 = 0.f;
#pragma unroll
    for (int c2 = 0; c2 < C2; ++c2) {
        v2h a2 = __builtin_bit_cast(v2h, a[c2]);
        const unsigned* br = &sB[c2 * 72 + x];   // tap dx at padded col x+dx
#pragma unroll
        for (int dx = 0; dx < PATCH; ++dx)
            acc[dx] = __builtin_amdgcn_fdot2(a2, __builtin_bit_cast(v2h, br[dx]),
                                             acc[dx], false);
        v2h c4 = __builtin_bit_cast(v2h, br[4]); // padded col x+4 == real col x
        ssq2 = __builtin_amdgcn_fdot2(c4, c4, ssq2, false);
    }
    sS2[x] = rsqrtf(ssq2 + 1e-6f);
    __syncthreads();                   // intra-wave LDS visibility

    const float s1 = rsqrtf(ssq1 + 1e-6f);
#pragma unroll
    for (int dx = 0; dx < PATCH; ++dx) {
        int col = x + dx - HALF;
        col = min(max(col, 0), WW - 1);          // OOB taps have acc==0
        ob[(dy * PATCH + dx) * HW] = fmaxf(acc[dx] * s1 * sS2[col], 0.f);
    }
}

extern "C" void kernel_launch(void* const* d_in, const int* in_sizes, int n_in,
                              void* d_out, int out_size, void* d_ws, size_t ws_size,
                              hipStream_t stream) {
    const float* f1 = (const float*)d_in[0];
    const float* f2 = (const float*)d_in[1];
    float* out = (float*)d_out;
    (void)d_ws; (void)ws_size;

    corr_kernel<<<BB * HH * PATCH, 64, 0, stream>>>(f1, f2, out);
}